// Round 14
// baseline (436.982 us; speedup 1.0000x reference)
//
#include <hip/hip_runtime.h>

typedef unsigned short u16;
typedef __attribute__((ext_vector_type(8))) short bf16x8;
typedef __attribute__((ext_vector_type(4))) float f32x4;

#define MFMA16(a,b,c) __builtin_amdgcn_mfma_f32_16x16x32_bf16((a),(b),(c),0,0,0)
#define BROW 48   // bucket = 48 dest rows; div via exact magic (r>>4)*43691>>17

static __device__ __forceinline__ u16 f2bf(float x){
    unsigned int u = __float_as_uint(x);
    u += 0x7FFFu + ((u >> 16) & 1u);
    return (u16)(u >> 16);
}
static __device__ __forceinline__ float bf2f(short s){
    return __uint_as_float(((unsigned int)(u16)s) << 16);
}
static __device__ __forceinline__ int div48(int r){ return ((r >> 4) * 43691) >> 17; }

static __device__ __forceinline__ bf16x8 load_bfrag(const float* __restrict__ W, int ldn, int n, int k0){
    bf16x8 r;
    #pragma unroll
    for (int j = 0; j < 8; ++j) r[j] = (short)f2bf(W[(k0 + j) * ldn + n]);
    return r;
}

// ---------------- encoder: h = relu(x@W1+b1)@W2 + b2 ; emit h, U0, V0 --------
__global__ __launch_bounds__(256) void enc_kernel(
    const float* __restrict__ X, const float* __restrict__ W1, const float* __restrict__ B1,
    const float* __restrict__ W2, const float* __restrict__ B2,
    const float* __restrict__ cW1, const float* __restrict__ cB1,   // conv layer-0
    u16* __restrict__ hbf, u16* __restrict__ Ubf, u16* __restrict__ Vbf, int N)
{
    __shared__ u16 sHid[64 * 136];
    __shared__ u16 sH[64 * 72];
    const int tid = threadIdx.x;
    const int w = tid >> 6, l = tid & 63, l15 = l & 15, quad = l >> 4;

    bf16x8 bW[4][4];
    #pragma unroll
    for (int ks = 0; ks < 4; ++ks)
        #pragma unroll
        for (int f = 0; f < 4; ++f)
            bW[ks][f] = load_bfrag(W2, 64, f * 16 + l15, ks * 32 + quad * 8);
    float b2v[4];
    #pragma unroll
    for (int f = 0; f < 4; ++f) b2v[f] = B2[f * 16 + l15];

    const int nbase = blockIdx.x * 64 + w * 16;

    {
        int e = l >> 2;
        int node = nbase + e; if (node > N - 1) node = N - 1;
        float x0 = X[node * 3], x1 = X[node * 3 + 1], x2 = X[node * 3 + 2];
        int k0 = (l & 3) * 32;
        u16* dst = sHid + (w * 16 + e) * 136 + k0;
        #pragma unroll
        for (int j = 0; j < 32; ++j){
            int k = k0 + j;
            float hv = x0 * W1[k] + x1 * W1[128 + k] + x2 * W1[256 + k] + B1[k];
            dst[j] = f2bf(hv > 0.f ? hv : 0.f);
        }
    }

    f32x4 acc[4];
    #pragma unroll
    for (int f = 0; f < 4; ++f){ acc[f][0]=b2v[f]; acc[f][1]=b2v[f]; acc[f][2]=b2v[f]; acc[f][3]=b2v[f]; }
    #pragma unroll
    for (int ks = 0; ks < 4; ++ks){
        bf16x8 a = *(const bf16x8*)&sHid[(w * 16 + l15) * 136 + ks * 32 + quad * 8];
        #pragma unroll
        for (int f = 0; f < 4; ++f) acc[f] = MFMA16(a, bW[ks][f], acc[f]);
    }
    #pragma unroll
    for (int r = 0; r < 4; ++r){
        int node = nbase + quad * 4 + r;
        #pragma unroll
        for (int f = 0; f < 4; ++f){
            u16 hb = f2bf(acc[f][r]);
            sH[(w * 16 + quad * 4 + r) * 72 + f * 16 + l15] = hb;
            if (node < N) hbf[(size_t)node * 64 + f * 16 + l15] = hb;
        }
    }

    bf16x8 bA[2][4], bB[2][4];
    #pragma unroll
    for (int kk = 0; kk < 2; ++kk)
        #pragma unroll
        for (int f = 0; f < 4; ++f){
            int n = f * 16 + l15, k0 = kk * 32 + quad * 8;
            bA[kk][f] = load_bfrag(cW1,           64, n, k0);
            bB[kk][f] = load_bfrag(cW1 + 64 * 64, 64, n, k0);
        }
    float b1n[4];
    #pragma unroll
    for (int f = 0; f < 4; ++f) b1n[f] = cB1[f * 16 + l15];

    bf16x8 a0 = *(const bf16x8*)&sH[(w * 16 + l15) * 72 + quad * 8];
    bf16x8 a1 = *(const bf16x8*)&sH[(w * 16 + l15) * 72 + 32 + quad * 8];

    f32x4 ua[4], va[4];
    #pragma unroll
    for (int f = 0; f < 4; ++f){
        ua[f][0]=b1n[f]; ua[f][1]=b1n[f]; ua[f][2]=b1n[f]; ua[f][3]=b1n[f];
        va[f][0]=0.f; va[f][1]=0.f; va[f][2]=0.f; va[f][3]=0.f;
    }
    #pragma unroll
    for (int f = 0; f < 4; ++f){ ua[f] = MFMA16(a0, bA[0][f], ua[f]); va[f] = MFMA16(a0, bB[0][f], va[f]); }
    #pragma unroll
    for (int f = 0; f < 4; ++f){ ua[f] = MFMA16(a1, bA[1][f], ua[f]); va[f] = MFMA16(a1, bB[1][f], va[f]); }

    #pragma unroll
    for (int r = 0; r < 4; ++r){
        int node = nbase + quad * 4 + r;
        if (node < N){
            #pragma unroll
            for (int f = 0; f < 4; ++f){
                Ubf[(size_t)node * 64 + f * 16 + l15] = f2bf(ua[f][r]);
                Vbf[(size_t)node * 64 + f * 16 + l15] = f2bf(va[f][r]);
            }
        }
    }
}

// ------------- bucket binning build (bucket = 48 dest rows, NB <= 2048) ------
__global__ __launch_bounds__(256) void countB_kernel(const int* __restrict__ rows,
                                                     int* __restrict__ countsB, int E, int NB){
    __shared__ int c[2048];
    for (int i = threadIdx.x; i < 2048; i += 256) c[i] = 0;
    __syncthreads();
    for (int i = blockIdx.x * 256 + threadIdx.x; i < E; i += gridDim.x * 256)
        atomicAdd(&c[div48(rows[i])], 1);
    __syncthreads();
    for (int i = threadIdx.x; i < NB; i += 256){
        int v = c[i];
        if (v) atomicAdd(&countsB[i], v);
    }
}

// single-block looped scan with carry (R12-verified)
__global__ __launch_bounds__(1024) void scanB_kernel(const int* __restrict__ countsB,
                                                     int* __restrict__ offsets,
                                                     int* __restrict__ cursorB, int n)
{
    __shared__ int wsum[16];
    __shared__ int carry_s;
    const int tid = threadIdx.x, lane = tid & 63, wv = tid >> 6;
    if (tid == 0) carry_s = 0;
    __syncthreads();
    for (int base = 0; base < n; base += 1024){
        int i = base + tid;
        int x = (i < n) ? countsB[i] : 0;
        int inc = x;
        #pragma unroll
        for (int d = 1; d < 64; d <<= 1){
            int t = __shfl_up(inc, d);
            if (lane >= d) inc += t;
        }
        if (lane == 63) wsum[wv] = inc;
        __syncthreads();
        if (tid < 16){
            int s = wsum[tid], si = s;
            #pragma unroll
            for (int d = 1; d < 16; d <<= 1){
                int t = __shfl_up(si, d);
                if (tid >= d) si += t;
            }
            wsum[tid] = si - s;
        }
        __syncthreads();
        int excl = inc - x + wsum[wv] + carry_s;
        if (i < n){ offsets[i] = excl; cursorB[i] = excl; }
        if (i == n - 1) offsets[n] = excl + x;
        __syncthreads();
        if (tid == 1023) carry_s += wsum[15] + inc;
        __syncthreads();
    }
}

#define CHUNK 8192

// chunk-local counting sort by 48-row bucket (R12-verified structure)
__global__ __launch_bounds__(1024) void binpack_kernel(
    const int* __restrict__ rows, const int* __restrict__ cols,
    const float* __restrict__ EF, int* __restrict__ cursorB,
    uint2* __restrict__ erec, int E)
{
    __shared__ u16 sRow[CHUNK];
    __shared__ u16 sPerm[CHUNK];
    __shared__ int cntA[2048];
    __shared__ int cntC[2048];
    __shared__ int baseB[2048];
    __shared__ u16 cntE[2048];
    __shared__ int wsum[16];
    const int tid = threadIdx.x, lane = tid & 63, wv = tid >> 6;
    const int cbase = blockIdx.x * CHUNK;
    int C = E - cbase; if (C > CHUNK) C = CHUNK;
    if (C <= 0) return;

    cntA[tid] = 0; cntA[tid + 1024] = 0;
    __syncthreads();
    for (int k = tid; k < C; k += 1024){
        int r = rows[cbase + k];
        sRow[k] = (u16)r;
        atomicAdd(&cntA[div48(r)], 1);
    }
    __syncthreads();
    int a = cntA[2 * tid], bq = cntA[2 * tid + 1];
    int x = a + bq;
    int inc = x;
    #pragma unroll
    for (int d = 1; d < 64; d <<= 1){
        int t = __shfl_up(inc, d);
        if (lane >= d) inc += t;
    }
    if (lane == 63) wsum[wv] = inc;
    __syncthreads();
    if (tid < 16){
        int s = wsum[tid], si = s;
        #pragma unroll
        for (int d = 1; d < 16; d <<= 1){
            int t = __shfl_up(si, d);
            if (tid >= d) si += t;
        }
        wsum[tid] = si - s;
    }
    __syncthreads();
    int excl = inc - x + wsum[wv];
    cntE[2 * tid] = (u16)excl;       cntE[2 * tid + 1] = (u16)(excl + a);
    cntC[2 * tid] = excl;            cntC[2 * tid + 1] = excl + a;
    if (a  > 0) baseB[2 * tid]     = atomicAdd(&cursorB[2 * tid],     a);
    if (bq > 0) baseB[2 * tid + 1] = atomicAdd(&cursorB[2 * tid + 1], bq);
    __syncthreads();
    for (int k = tid; k < C; k += 1024){
        int bk = div48((int)sRow[k]);
        int p = atomicAdd(&cntC[bk], 1);
        sPerm[p] = (u16)k;
    }
    __syncthreads();
    for (int p = tid; p < C; p += 1024){
        int k = sPerm[p];
        int i = cbase + k;
        int r = sRow[k];
        int bk = div48(r);
        float2 ef = *(const float2*)&EF[2 * i];
        uint2 v;
        v.x = (unsigned)r | ((unsigned)cols[i] << 16);
        v.y = (unsigned)f2bf(ef.x) | ((unsigned)f2bf(ef.y) << 16);
        erec[baseB[bk] + (p - (int)cntE[bk])] = v;
    }
}

// issue U/V gathers for a record (loads start here; waited at first use)
#define ISSUE_UV(recv, U0, U1, V0, V1) do {                                  \
    int rr_ = (int)((recv).x & 0xFFFFu); if (rr_ == 0xFFFF) rr_ = 0;         \
    int cc_ = (int)((recv).x >> 16);                                         \
    const u16* pu_ = Ubf + (size_t)rr_ * 64 + quad * 8;                      \
    const u16* pv_ = Vbf + (size_t)cc_ * 64 + quad * 8;                      \
    U0 = *(const bf16x8*)(pu_);                                              \
    U1 = *(const bf16x8*)(pu_ + 32);                                         \
    V0 = *(const bf16x8*)(pv_);                                              \
    V1 = *(const bf16x8*)(pv_ + 32);                                         \
} while (0)

// pack 2 floats -> 1 dword of 2 bf16 (RTNE), src0 -> low half
static __device__ __forceinline__ unsigned cvtpk(float a, float b){
    unsigned d;
    asm("v_cvt_pk_bf16_f32 %0, %1, %2" : "=v"(d) : "v"(a), "v"(b));
    return d;
}
#define PACK8(dst, x) do {                                                   \
    union { bf16x8 v; unsigned int d[4]; } _u;                               \
    _u.d[0] = cvtpk(x[0], x[1]); _u.d[1] = cvtpk(x[2], x[3]);                \
    _u.d[2] = cvtpk(x[4], x[5]); _u.d[3] = cvtpk(x[6], x[7]);                \
    dst = _u.v;                                                              \
} while (0)

// ==== fused layer (R13 structure, 3-deep U/V prefetch): msgs + MFMA scatter ==
// one block (4 waves) per 48-row bucket; wave w owns rows w*16..w*16+15
// (wave 3 idle rows); no global atomics; agg never in memory.
__global__ __launch_bounds__(256, 3) void fused_kernel(
    const u16* __restrict__ Ubf, const u16* __restrict__ Vbf,   // this layer U/V
    const uint2* __restrict__ erec, const int* __restrict__ offsets,
    const float* __restrict__ W1,   // conv W1 [130][64] (ef rows 128,129)
    const float* __restrict__ W2, const float* __restrict__ B2,
    u16* __restrict__ hbf,
    const float* __restrict__ SW, const float* __restrict__ SB,
    const float* __restrict__ LG, const float* __restrict__ LB,
    const float* __restrict__ cW1, const float* __restrict__ cB1, // next layer (may be null)
    u16* __restrict__ Un, u16* __restrict__ Vn,                   // next layer U/V out
    int N)
{
    __shared__ u16 sMsgT[2][64 * 72];   // feat-major bf16 messages, dbuf
    __shared__ u16 sRowT[2][64];        // local row per edge slot (0xFFFF pad)
    __shared__ u16 sH[64 * 72];
    const int tid = threadIdx.x;
    const int w = tid >> 6, l = tid & 63, l15 = l & 15, quad = l >> 4;
    const int w16 = w * 16;

    // message-phase weights
    bf16x8 bW2[2][4];
    #pragma unroll
    for (int kk = 0; kk < 2; ++kk)
        #pragma unroll
        for (int f = 0; f < 4; ++f)
            bW2[kk][f] = load_bfrag(W2, 64, f * 16 + l15, kk * 32 + quad * 8);
    float bias2[4];
    #pragma unroll
    for (int f = 0; f < 4; ++f) bias2[f] = B2[f * 16 + l15];

    // ef-row weights, packed bf16 (k = quad*8+j lo / 32+quad*8+j hi)
    const float* Wc0 = W1 + 128 * 64;
    const float* Wc1 = W1 + 129 * 64;
    bf16x8 e0lo, e0hi, e1lo, e1hi;
    #pragma unroll
    for (int j = 0; j < 8; ++j){
        int kl = quad * 8 + j;
        e0lo[j] = (short)f2bf(Wc0[kl]);      e0hi[j] = (short)f2bf(Wc0[32 + kl]);
        e1lo[j] = (short)f2bf(Wc1[kl]);      e1hi[j] = (short)f2bf(Wc1[32 + kl]);
    }

    const int b = blockIdx.x;
    const int start = offsets[b], end = offsets[b + 1];
    const int nt = (end - start + 63) >> 6;
    const int rowbase = b * BROW;
    const int tgtrow = w16 + l15;       // lane's owned local row (48..63 idle)

    f32x4 aggC[4] = {};                  // wave's 16 rows x 64 feats, C layout

    auto LOADREC = [&](int t) -> uint2 {
        int e = start + t * 64 + w16 + l15;
        if (e < end) return erec[e];
        uint2 s; s.x = 0x0000FFFFu; s.y = 0u; return s;
    };

    if (nt > 0){
        // 3-deep pipeline: recs 3 ahead, U/V gathers 2 ahead
        uint2 recA = LOADREC(0);
        uint2 recB = LOADREC(1);
        uint2 recC = LOADREC(2);
        bf16x8 u0, u1, v0, v1;          // tile t   (landed / in use)
        bf16x8 p0, p1, p2, p3;          // tile t+1 (in flight)
        ISSUE_UV(recA, u0, u1, v0, v1);
        ISSUE_UV(recB, p0, p1, p2, p3);

        for (int t = 0; t < nt; ++t){
            uint2 recD = LOADREC(t + 3);
            bf16x8 q0, q1, q2, q3;      // tile t+2 gathers start now
            ISSUE_UV(recC, q0, q1, q2, q3);

            int rn_raw = (int)(recA.x & 0xFFFFu);
            float ef0 = bf2f((short)(recA.y & 0xFFFFu));
            float ef1 = bf2f((short)(recA.y >> 16));

            float xl[8], xh[8];
            #pragma unroll
            for (int j = 0; j < 8; ++j){
                float hA = fmaf(ef1, bf2f(e1lo[j]), ef0 * bf2f(e0lo[j]));
                float hB = fmaf(ef1, bf2f(e1hi[j]), ef0 * bf2f(e0hi[j]));
                xl[j] = fmaxf(hA + bf2f(u0[j]) + bf2f(v0[j]), 0.f);
                xh[j] = fmaxf(hB + bf2f(u1[j]) + bf2f(v1[j]), 0.f);
            }
            bf16x8 a0, a1;
            PACK8(a0, xl);
            PACK8(a1, xh);

            f32x4 m[4];
            #pragma unroll
            for (int f = 0; f < 4; ++f){ m[f][0]=bias2[f]; m[f][1]=bias2[f]; m[f][2]=bias2[f]; m[f][3]=bias2[f]; }
            #pragma unroll
            for (int f = 0; f < 4; ++f) m[f] = MFMA16(a0, bW2[0][f], m[f]);
            #pragma unroll
            for (int f = 0; f < 4; ++f) m[f] = MFMA16(a1, bW2[1][f], m[f]);

            // transposed (feat-major) bf16 messages -> LDS
            const int buf = t & 1;
            #pragma unroll
            for (int f = 0; f < 4; ++f){
                uint2 wv;
                wv.x = cvtpk(m[f][0], m[f][1]);
                wv.y = cvtpk(m[f][2], m[f][3]);
                *(uint2*)&sMsgT[buf][(f * 16 + l15) * 72 + w16 + quad * 4] = wv;
            }
            if (quad == 0)
                sRowT[buf][w16 + l15] = (rn_raw == 0xFFFF) ? (u16)0xFFFF
                                                           : (u16)(rn_raw - rowbase);

            __syncthreads();

            // scatter: aggC += S (onehot rows) x M  (2 e-chunks x 4 f-chunks)
            #pragma unroll
            for (int c = 0; c < 2; ++c){
                union { bf16x8 v; unsigned d[4]; } sfr;
                union { uint4 q; unsigned d[4]; } rv;
                rv.q = *(const uint4*)&sRowT[buf][c * 32 + quad * 8];
                #pragma unroll
                for (int k = 0; k < 4; ++k){
                    unsigned d = rv.d[k];
                    unsigned lo = d & 0xFFFFu, hi = d >> 16;
                    sfr.d[k] = (lo == (unsigned)tgtrow ? 0x3F80u : 0u)
                             | (hi == (unsigned)tgtrow ? 0x3F800000u : 0u);
                }
                #pragma unroll
                for (int f = 0; f < 4; ++f){
                    bf16x8 mb = *(const bf16x8*)&sMsgT[buf][(f * 16 + l15) * 72 + c * 32 + quad * 8];
                    aggC[f] = MFMA16(sfr.v, mb, aggC[f]);
                }
            }
            // no 2nd barrier: next tile writes the other buffer

            recA = recB; recB = recC; recC = recD;
            u0 = p0; u1 = p1; v0 = p2; v1 = p3;
            p0 = q0; p1 = q1; p2 = q2; p3 = q3;
        }
    }

    __syncthreads();                     // all scatter reads done

    if (w < 3){
        // ------------- fused update: h = relu(LN(aggC + h@SW + SB)) ----------
        bf16x8 bW[2][4];
        #pragma unroll
        for (int kk = 0; kk < 2; ++kk)
            #pragma unroll
            for (int f = 0; f < 4; ++f)
                bW[kk][f] = load_bfrag(SW, 64, f * 16 + l15, kk * 32 + quad * 8);
        float sb[4], lg[4], lb[4];
        #pragma unroll
        for (int f = 0; f < 4; ++f){
            int n = f * 16 + l15;
            sb[f] = SB[n]; lg[f] = LG[n]; lb[f] = LB[n];
        }

        const int nbase = rowbase + w16;
        int na = nbase + l15; if (na > N - 1) na = N - 1;
        const u16* pa = hbf + (size_t)na * 64 + quad * 8;
        bf16x8 h0 = *(const bf16x8*)pa;
        bf16x8 h1 = *(const bf16x8*)(pa + 32);

        f32x4 acc[4] = {};
        #pragma unroll
        for (int f = 0; f < 4; ++f) acc[f] = MFMA16(h0, bW[0][f], acc[f]);
        #pragma unroll
        for (int f = 0; f < 4; ++f) acc[f] = MFMA16(h1, bW[1][f], acc[f]);

        float vals[4][4];
        #pragma unroll
        for (int r = 0; r < 4; ++r)
            #pragma unroll
            for (int f = 0; f < 4; ++f)
                vals[f][r] = acc[f][r] + sb[f] + aggC[f][r];

        #pragma unroll
        for (int r = 0; r < 4; ++r){
            float s  = vals[0][r] + vals[1][r] + vals[2][r] + vals[3][r];
            float sq = vals[0][r]*vals[0][r] + vals[1][r]*vals[1][r]
                     + vals[2][r]*vals[2][r] + vals[3][r]*vals[3][r];
            #pragma unroll
            for (int msk = 1; msk < 16; msk <<= 1){
                s  += __shfl_xor(s,  msk);
                sq += __shfl_xor(sq, msk);
            }
            float mean = s * (1.f / 64.f);
            float var  = sq * (1.f / 64.f) - mean * mean;
            float rstd = rsqrtf(var + 1e-5f);
            int node = nbase + quad * 4 + r;
            #pragma unroll
            for (int f = 0; f < 4; ++f){
                float hv = (vals[f][r] - mean) * rstd * lg[f] + lb[f];
                hv = hv > 0.f ? hv : 0.f;
                u16 hb = f2bf(hv);
                sH[(w16 + quad * 4 + r) * 72 + f * 16 + l15] = hb;
                if (node < N) hbf[(size_t)node * 64 + f * 16 + l15] = hb;
            }
        }

        if (cW1){
            bf16x8 bA[2][4], bB[2][4];
            #pragma unroll
            for (int kk = 0; kk < 2; ++kk)
                #pragma unroll
                for (int f = 0; f < 4; ++f){
                    int n = f * 16 + l15, k0 = kk * 32 + quad * 8;
                    bA[kk][f] = load_bfrag(cW1,           64, n, k0);
                    bB[kk][f] = load_bfrag(cW1 + 64 * 64, 64, n, k0);
                }
            float b1n[4];
            #pragma unroll
            for (int f = 0; f < 4; ++f) b1n[f] = cB1[f * 16 + l15];

            bf16x8 a0 = *(const bf16x8*)&sH[(w16 + l15) * 72 + quad * 8];
            bf16x8 a1 = *(const bf16x8*)&sH[(w16 + l15) * 72 + 32 + quad * 8];

            f32x4 ua[4], va[4];
            #pragma unroll
            for (int f = 0; f < 4; ++f){
                ua[f][0]=b1n[f]; ua[f][1]=b1n[f]; ua[f][2]=b1n[f]; ua[f][3]=b1n[f];
                va[f][0]=0.f; va[f][1]=0.f; va[f][2]=0.f; va[f][3]=0.f;
            }
            #pragma unroll
            for (int f = 0; f < 4; ++f){ ua[f] = MFMA16(a0, bA[0][f], ua[f]); va[f] = MFMA16(a0, bB[0][f], va[f]); }
            #pragma unroll
            for (int f = 0; f < 4; ++f){ ua[f] = MFMA16(a1, bA[1][f], ua[f]); va[f] = MFMA16(a1, bB[1][f], va[f]); }

            #pragma unroll
            for (int r = 0; r < 4; ++r){
                int node = nbase + quad * 4 + r;
                if (node < N){
                    #pragma unroll
                    for (int f = 0; f < 4; ++f){
                        Un[(size_t)node * 64 + f * 16 + l15] = f2bf(ua[f][r]);
                        Vn[(size_t)node * 64 + f * 16 + l15] = f2bf(va[f][r]);
                    }
                }
            }
        }
    }
}

// ---------------- head: out = relu(h@W1+b1)@W2 + b2  [N][8] f32 --------------
__global__ __launch_bounds__(256) void head_kernel(
    const u16* __restrict__ hbf,
    const float* __restrict__ W1, const float* __restrict__ B1,
    const float* __restrict__ W2, const float* __restrict__ B2,
    float* __restrict__ out, int N)
{
    __shared__ u16 sT[64 * 72];
    const int tid = threadIdx.x;
    const int w = tid >> 6, l = tid & 63, l15 = l & 15, quad = l >> 4;

    bf16x8 bW1[2][4];
    #pragma unroll
    for (int kk = 0; kk < 2; ++kk)
        #pragma unroll
        for (int f = 0; f < 4; ++f)
            bW1[kk][f] = load_bfrag(W1, 64, f * 16 + l15, kk * 32 + quad * 8);
    float b1v[4];
    #pragma unroll
    for (int f = 0; f < 4; ++f) b1v[f] = B1[f * 16 + l15];

    bf16x8 bW2[2];
    #pragma unroll
    for (int kk = 0; kk < 2; ++kk)
        #pragma unroll
        for (int j = 0; j < 8; ++j){
            int k = kk * 32 + quad * 8 + j;
            bW2[kk][j] = (l15 < 8) ? (short)f2bf(W2[k * 8 + l15]) : (short)0;
        }
    float b2v = (l15 < 8) ? B2[l15] : 0.f;

    const int nbase = blockIdx.x * 64 + w * 16;
    int na = nbase + l15; if (na > N - 1) na = N - 1;
    const u16* pa = hbf + (size_t)na * 64 + quad * 8;
    bf16x8 a0 = *(const bf16x8*)pa;
    bf16x8 a1 = *(const bf16x8*)(pa + 32);

    f32x4 acc[4];
    #pragma unroll
    for (int f = 0; f < 4; ++f){ acc[f][0]=b1v[f]; acc[f][1]=b1v[f]; acc[f][2]=b1v[f]; acc[f][3]=b1v[f]; }
    #pragma unroll
    for (int f = 0; f < 4; ++f) acc[f] = MFMA16(a0, bW1[0][f], acc[f]);
    #pragma unroll
    for (int f = 0; f < 4; ++f) acc[f] = MFMA16(a1, bW1[1][f], acc[f]);

    u16* myT = sT + (w * 16) * 72;
    #pragma unroll
    for (int f = 0; f < 4; ++f)
        #pragma unroll
        for (int r = 0; r < 4; ++r){
            float v = acc[f][r] > 0.f ? acc[f][r] : 0.f;
            myT[(quad * 4 + r) * 72 + f * 16 + l15] = f2bf(v);
        }

    f32x4 o = { b2v, b2v, b2v, b2v };
    #pragma unroll
    for (int kk = 0; kk < 2; ++kk){
        bf16x8 a = *(const bf16x8*)&myT[l15 * 72 + kk * 32 + quad * 8];
        o = MFMA16(a, bW2[kk], o);
    }
    #pragma unroll
    for (int r = 0; r < 4; ++r){
        int node = nbase + quad * 4 + r;
        if (node < N && l15 < 8)
            out[(size_t)node * 8 + l15] = o[r];
    }
}

extern "C" void kernel_launch(void* const* d_in, const int* in_sizes, int n_in,
                              void* d_out, int out_size, void* d_ws, size_t ws_size,
                              hipStream_t stream)
{
    const float* X      = (const float*)d_in[0];
    const int*   EI     = (const int*)d_in[1];
    const float* EF     = (const float*)d_in[2];
    const float* encW1  = (const float*)d_in[4];
    const float* encB1  = (const float*)d_in[5];
    const float* encW2  = (const float*)d_in[6];
    const float* encB2  = (const float*)d_in[7];
    const float* convW1 = (const float*)d_in[8];
    const float* convB1 = (const float*)d_in[9];
    const float* convW2 = (const float*)d_in[10];
    const float* convB2 = (const float*)d_in[11];
    const float* skipW  = (const float*)d_in[12];
    const float* skipB  = (const float*)d_in[13];
    const float* lnG    = (const float*)d_in[14];
    const float* lnB    = (const float*)d_in[15];
    const float* headW1 = (const float*)d_in[16];
    const float* headB1 = (const float*)d_in[17];
    const float* headW2 = (const float*)d_in[18];
    const float* headB2 = (const float*)d_in[19];

    const int N = in_sizes[0] / 3;      // NOTE: packing assumes N < 65535
    const int E = in_sizes[1] / 2;
    const int L = in_sizes[8] / (130 * 64);
    const int* rows = EI;
    const int* cols = EI + E;

    const int NB64 = (N + 63) / 64;     // 64-node tiles (enc/head)
    const int NB48 = (N + 47) / 48;     // 48-row buckets (fused), <= 2048

    auto align256 = [](size_t x){ return (x + 255) & ~(size_t)255; };
    char* p = (char*)d_ws;
    u16* hbf   = (u16*)p;           p += align256((size_t)N * 64 * 2);
    u16* Ubuf0 = (u16*)p;           p += align256((size_t)N * 64 * 2);
    u16* Vbuf0 = (u16*)p;           p += align256((size_t)N * 64 * 2);
    u16* Ubuf1 = (u16*)p;           p += align256((size_t)N * 64 * 2);
    u16* Vbuf1 = (u16*)p;           p += align256((size_t)N * 64 * 2);
    uint2* erec = (uint2*)p;        p += align256((size_t)E * 8);
    int* countsB = (int*)p;         p += align256(2048 * 4);
    int* offsets = (int*)p;         p += align256(2056 * 4);
    int* cursorB = (int*)p;         p += align256(2048 * 4);

    // ---- build 48-row-bucket binned packed edge records (once per call) ----
    hipMemsetAsync(countsB, 0, (size_t)NB48 * sizeof(int), stream);
    countB_kernel<<<256, 256, 0, stream>>>(rows, countsB, E, NB48);
    scanB_kernel<<<1, 1024, 0, stream>>>(countsB, offsets, cursorB, NB48);
    binpack_kernel<<<(E + CHUNK - 1) / CHUNK, 1024, 0, stream>>>(rows, cols, EF, cursorB, erec, E);

    enc_kernel<<<NB64, 256, 0, stream>>>(X, encW1, encB1, encW2, encB2,
                                         convW1, convB1, hbf, Ubuf0, Vbuf0, N);

    u16* Ucur = Ubuf0; u16* Vcur = Vbuf0;
    u16* Ualt = Ubuf1; u16* Valt = Vbuf1;
    for (int li = 0; li < L; ++li){
        const float* w1n = (li + 1 < L) ? convW1 + (size_t)(li + 1) * 130 * 64 : nullptr;
        const float* b1n = (li + 1 < L) ? convB1 + (li + 1) * 64 : nullptr;
        fused_kernel<<<NB48, 256, 0, stream>>>(Ucur, Vcur, erec, offsets,
            convW1 + (size_t)li * 130 * 64,
            convW2 + (size_t)li * 64 * 64, convB2 + li * 64,
            hbf,
            skipW + (size_t)li * 64 * 64, skipB + li * 64,
            lnG + li * 64, lnB + li * 64,
            w1n, b1n, Ualt, Valt, N);
        u16* t;
        t = Ucur; Ucur = Ualt; Ualt = t;
        t = Vcur; Vcur = Valt; Valt = t;
    }
    head_kernel<<<NB64, 256, 0, stream>>>(hbf, headW1, headB1, headW2, headB2,
                                          (float*)d_out, N);
}

// Round 15
// 306.583 us; speedup vs baseline: 1.4253x; 1.4253x over previous
//
#include <hip/hip_runtime.h>

typedef unsigned short u16;
typedef __attribute__((ext_vector_type(8))) short bf16x8;
typedef __attribute__((ext_vector_type(4))) float f32x4;

#define MFMA16(a,b,c) __builtin_amdgcn_mfma_f32_16x16x32_bf16((a),(b),(c),0,0,0)
#define BROW 48   // bucket = 48 dest rows; div via exact magic (r>>4)*43691>>17

static __device__ __forceinline__ u16 f2bf(float x){
    unsigned int u = __float_as_uint(x);
    u += 0x7FFFu + ((u >> 16) & 1u);
    return (u16)(u >> 16);
}
static __device__ __forceinline__ float bf2f(short s){
    return __uint_as_float(((unsigned int)(u16)s) << 16);
}
static __device__ __forceinline__ int div48(int r){ return ((r >> 4) * 43691) >> 17; }

static __device__ __forceinline__ bf16x8 load_bfrag(const float* __restrict__ W, int ldn, int n, int k0){
    bf16x8 r;
    #pragma unroll
    for (int j = 0; j < 8; ++j) r[j] = (short)f2bf(W[(k0 + j) * ldn + n]);
    return r;
}

// ---------------- encoder: h = relu(x@W1+b1)@W2 + b2 ; emit h, U0, V0 --------
__global__ __launch_bounds__(256) void enc_kernel(
    const float* __restrict__ X, const float* __restrict__ W1, const float* __restrict__ B1,
    const float* __restrict__ W2, const float* __restrict__ B2,
    const float* __restrict__ cW1, const float* __restrict__ cB1,   // conv layer-0
    u16* __restrict__ hbf, u16* __restrict__ Ubf, u16* __restrict__ Vbf, int N)
{
    __shared__ u16 sHid[64 * 136];
    __shared__ u16 sH[64 * 72];
    const int tid = threadIdx.x;
    const int w = tid >> 6, l = tid & 63, l15 = l & 15, quad = l >> 4;

    bf16x8 bW[4][4];
    #pragma unroll
    for (int ks = 0; ks < 4; ++ks)
        #pragma unroll
        for (int f = 0; f < 4; ++f)
            bW[ks][f] = load_bfrag(W2, 64, f * 16 + l15, ks * 32 + quad * 8);
    float b2v[4];
    #pragma unroll
    for (int f = 0; f < 4; ++f) b2v[f] = B2[f * 16 + l15];

    const int nbase = blockIdx.x * 64 + w * 16;

    {
        int e = l >> 2;
        int node = nbase + e; if (node > N - 1) node = N - 1;
        float x0 = X[node * 3], x1 = X[node * 3 + 1], x2 = X[node * 3 + 2];
        int k0 = (l & 3) * 32;
        u16* dst = sHid + (w * 16 + e) * 136 + k0;
        #pragma unroll
        for (int j = 0; j < 32; ++j){
            int k = k0 + j;
            float hv = x0 * W1[k] + x1 * W1[128 + k] + x2 * W1[256 + k] + B1[k];
            dst[j] = f2bf(hv > 0.f ? hv : 0.f);
        }
    }

    f32x4 acc[4];
    #pragma unroll
    for (int f = 0; f < 4; ++f){ acc[f][0]=b2v[f]; acc[f][1]=b2v[f]; acc[f][2]=b2v[f]; acc[f][3]=b2v[f]; }
    #pragma unroll
    for (int ks = 0; ks < 4; ++ks){
        bf16x8 a = *(const bf16x8*)&sHid[(w * 16 + l15) * 136 + ks * 32 + quad * 8];
        #pragma unroll
        for (int f = 0; f < 4; ++f) acc[f] = MFMA16(a, bW[ks][f], acc[f]);
    }
    #pragma unroll
    for (int r = 0; r < 4; ++r){
        int node = nbase + quad * 4 + r;
        #pragma unroll
        for (int f = 0; f < 4; ++f){
            u16 hb = f2bf(acc[f][r]);
            sH[(w * 16 + quad * 4 + r) * 72 + f * 16 + l15] = hb;
            if (node < N) hbf[(size_t)node * 64 + f * 16 + l15] = hb;
        }
    }

    bf16x8 bA[2][4], bB[2][4];
    #pragma unroll
    for (int kk = 0; kk < 2; ++kk)
        #pragma unroll
        for (int f = 0; f < 4; ++f){
            int n = f * 16 + l15, k0 = kk * 32 + quad * 8;
            bA[kk][f] = load_bfrag(cW1,           64, n, k0);
            bB[kk][f] = load_bfrag(cW1 + 64 * 64, 64, n, k0);
        }
    float b1n[4];
    #pragma unroll
    for (int f = 0; f < 4; ++f) b1n[f] = cB1[f * 16 + l15];

    bf16x8 a0 = *(const bf16x8*)&sH[(w * 16 + l15) * 72 + quad * 8];
    bf16x8 a1 = *(const bf16x8*)&sH[(w * 16 + l15) * 72 + 32 + quad * 8];

    f32x4 ua[4], va[4];
    #pragma unroll
    for (int f = 0; f < 4; ++f){
        ua[f][0]=b1n[f]; ua[f][1]=b1n[f]; ua[f][2]=b1n[f]; ua[f][3]=b1n[f];
        va[f][0]=0.f; va[f][1]=0.f; va[f][2]=0.f; va[f][3]=0.f;
    }
    #pragma unroll
    for (int f = 0; f < 4; ++f){ ua[f] = MFMA16(a0, bA[0][f], ua[f]); va[f] = MFMA16(a0, bB[0][f], va[f]); }
    #pragma unroll
    for (int f = 0; f < 4; ++f){ ua[f] = MFMA16(a1, bA[1][f], ua[f]); va[f] = MFMA16(a1, bB[1][f], va[f]); }

    #pragma unroll
    for (int r = 0; r < 4; ++r){
        int node = nbase + quad * 4 + r;
        if (node < N){
            #pragma unroll
            for (int f = 0; f < 4; ++f){
                Ubf[(size_t)node * 64 + f * 16 + l15] = f2bf(ua[f][r]);
                Vbf[(size_t)node * 64 + f * 16 + l15] = f2bf(va[f][r]);
            }
        }
    }
}

// ------------- bucket binning build (bucket = 48 dest rows, NB <= 2048) ------
__global__ __launch_bounds__(256) void countB_kernel(const int* __restrict__ rows,
                                                     int* __restrict__ countsB, int E, int NB){
    __shared__ int c[2048];
    for (int i = threadIdx.x; i < 2048; i += 256) c[i] = 0;
    __syncthreads();
    for (int i = blockIdx.x * 256 + threadIdx.x; i < E; i += gridDim.x * 256)
        atomicAdd(&c[div48(rows[i])], 1);
    __syncthreads();
    for (int i = threadIdx.x; i < NB; i += 256){
        int v = c[i];
        if (v) atomicAdd(&countsB[i], v);
    }
}

// single-block looped scan with carry (R12-verified)
__global__ __launch_bounds__(1024) void scanB_kernel(const int* __restrict__ countsB,
                                                     int* __restrict__ offsets,
                                                     int* __restrict__ cursorB, int n)
{
    __shared__ int wsum[16];
    __shared__ int carry_s;
    const int tid = threadIdx.x, lane = tid & 63, wv = tid >> 6;
    if (tid == 0) carry_s = 0;
    __syncthreads();
    for (int base = 0; base < n; base += 1024){
        int i = base + tid;
        int x = (i < n) ? countsB[i] : 0;
        int inc = x;
        #pragma unroll
        for (int d = 1; d < 64; d <<= 1){
            int t = __shfl_up(inc, d);
            if (lane >= d) inc += t;
        }
        if (lane == 63) wsum[wv] = inc;
        __syncthreads();
        if (tid < 16){
            int s = wsum[tid], si = s;
            #pragma unroll
            for (int d = 1; d < 16; d <<= 1){
                int t = __shfl_up(si, d);
                if (tid >= d) si += t;
            }
            wsum[tid] = si - s;
        }
        __syncthreads();
        int excl = inc - x + wsum[wv] + carry_s;
        if (i < n){ offsets[i] = excl; cursorB[i] = excl; }
        if (i == n - 1) offsets[n] = excl + x;
        __syncthreads();
        if (tid == 1023) carry_s += wsum[15] + inc;
        __syncthreads();
    }
}

#define CHUNK 8192

// chunk-local counting sort by 48-row bucket (R12-verified structure)
__global__ __launch_bounds__(1024) void binpack_kernel(
    const int* __restrict__ rows, const int* __restrict__ cols,
    const float* __restrict__ EF, int* __restrict__ cursorB,
    uint2* __restrict__ erec, int E)
{
    __shared__ u16 sRow[CHUNK];
    __shared__ u16 sPerm[CHUNK];
    __shared__ int cntA[2048];
    __shared__ int cntC[2048];
    __shared__ int baseB[2048];
    __shared__ u16 cntE[2048];
    __shared__ int wsum[16];
    const int tid = threadIdx.x, lane = tid & 63, wv = tid >> 6;
    const int cbase = blockIdx.x * CHUNK;
    int C = E - cbase; if (C > CHUNK) C = CHUNK;
    if (C <= 0) return;

    cntA[tid] = 0; cntA[tid + 1024] = 0;
    __syncthreads();
    for (int k = tid; k < C; k += 1024){
        int r = rows[cbase + k];
        sRow[k] = (u16)r;
        atomicAdd(&cntA[div48(r)], 1);
    }
    __syncthreads();
    int a = cntA[2 * tid], bq = cntA[2 * tid + 1];
    int x = a + bq;
    int inc = x;
    #pragma unroll
    for (int d = 1; d < 64; d <<= 1){
        int t = __shfl_up(inc, d);
        if (lane >= d) inc += t;
    }
    if (lane == 63) wsum[wv] = inc;
    __syncthreads();
    if (tid < 16){
        int s = wsum[tid], si = s;
        #pragma unroll
        for (int d = 1; d < 16; d <<= 1){
            int t = __shfl_up(si, d);
            if (tid >= d) si += t;
        }
        wsum[tid] = si - s;
    }
    __syncthreads();
    int excl = inc - x + wsum[wv];
    cntE[2 * tid] = (u16)excl;       cntE[2 * tid + 1] = (u16)(excl + a);
    cntC[2 * tid] = excl;            cntC[2 * tid + 1] = excl + a;
    if (a  > 0) baseB[2 * tid]     = atomicAdd(&cursorB[2 * tid],     a);
    if (bq > 0) baseB[2 * tid + 1] = atomicAdd(&cursorB[2 * tid + 1], bq);
    __syncthreads();
    for (int k = tid; k < C; k += 1024){
        int bk = div48((int)sRow[k]);
        int p = atomicAdd(&cntC[bk], 1);
        sPerm[p] = (u16)k;
    }
    __syncthreads();
    for (int p = tid; p < C; p += 1024){
        int k = sPerm[p];
        int i = cbase + k;
        int r = sRow[k];
        int bk = div48(r);
        float2 ef = *(const float2*)&EF[2 * i];
        uint2 v;
        v.x = (unsigned)r | ((unsigned)cols[i] << 16);
        v.y = (unsigned)f2bf(ef.x) | ((unsigned)f2bf(ef.y) << 16);
        erec[baseB[bk] + (p - (int)cntE[bk])] = v;
    }
}

// issue U/V gathers for a record (loads start here; waited at first use)
#define ISSUE_UV(recv, U0, U1, V0, V1) do {                                  \
    int rr_ = (int)((recv).x & 0xFFFFu); if (rr_ == 0xFFFF) rr_ = 0;         \
    int cc_ = (int)((recv).x >> 16);                                         \
    const u16* pu_ = Ubf + (size_t)rr_ * 64 + quad * 8;                      \
    const u16* pv_ = Vbf + (size_t)cc_ * 64 + quad * 8;                      \
    U0 = *(const bf16x8*)(pu_);                                              \
    U1 = *(const bf16x8*)(pu_ + 32);                                         \
    V0 = *(const bf16x8*)(pv_);                                              \
    V1 = *(const bf16x8*)(pv_ + 32);                                         \
} while (0)

// pack 2 floats -> 1 dword of 2 bf16 (RTNE), src0 -> low half
static __device__ __forceinline__ unsigned cvtpk(float a, float b){
    unsigned d;
    asm("v_cvt_pk_bf16_f32 %0, %1, %2" : "=v"(d) : "v"(a), "v"(b));
    return d;
}
#define PACK8(dst, x) do {                                                   \
    union { bf16x8 v; unsigned int d[4]; } _u;                               \
    _u.d[0] = cvtpk(x[0], x[1]); _u.d[1] = cvtpk(x[2], x[3]);                \
    _u.d[2] = cvtpk(x[4], x[5]); _u.d[3] = cvtpk(x[6], x[7]);                \
    dst = _u.v;                                                              \
} while (0)

// ==== fused layer (R13 = best verified): messages + S-matrix MFMA scatter ====
// one block (4 waves) per 48-row bucket; wave w owns rows w*16..w*16+15
// (wave 3 idle rows); no global atomics; agg never in memory.
// VGPR 84 / no spill at __launch_bounds__(256,3) — do not restructure (R9/R10/
// R12/R14 all lost to regalloc side effects).
__global__ __launch_bounds__(256, 3) void fused_kernel(
    const u16* __restrict__ Ubf, const u16* __restrict__ Vbf,   // this layer U/V
    const uint2* __restrict__ erec, const int* __restrict__ offsets,
    const float* __restrict__ W1,   // conv W1 [130][64] (ef rows 128,129)
    const float* __restrict__ W2, const float* __restrict__ B2,
    u16* __restrict__ hbf,
    const float* __restrict__ SW, const float* __restrict__ SB,
    const float* __restrict__ LG, const float* __restrict__ LB,
    const float* __restrict__ cW1, const float* __restrict__ cB1, // next layer (may be null)
    u16* __restrict__ Un, u16* __restrict__ Vn,                   // next layer U/V out
    int N)
{
    __shared__ u16 sMsgT[2][64 * 72];   // feat-major bf16 messages, dbuf
    __shared__ u16 sRowT[2][64];        // local row per edge slot (0xFFFF pad)
    __shared__ u16 sH[64 * 72];
    const int tid = threadIdx.x;
    const int w = tid >> 6, l = tid & 63, l15 = l & 15, quad = l >> 4;
    const int w16 = w * 16;

    // message-phase weights
    bf16x8 bW2[2][4];
    #pragma unroll
    for (int kk = 0; kk < 2; ++kk)
        #pragma unroll
        for (int f = 0; f < 4; ++f)
            bW2[kk][f] = load_bfrag(W2, 64, f * 16 + l15, kk * 32 + quad * 8);
    float bias2[4];
    #pragma unroll
    for (int f = 0; f < 4; ++f) bias2[f] = B2[f * 16 + l15];

    // ef-row weights, packed bf16 (k = quad*8+j lo / 32+quad*8+j hi)
    const float* Wc0 = W1 + 128 * 64;
    const float* Wc1 = W1 + 129 * 64;
    bf16x8 e0lo, e0hi, e1lo, e1hi;
    #pragma unroll
    for (int j = 0; j < 8; ++j){
        int kl = quad * 8 + j;
        e0lo[j] = (short)f2bf(Wc0[kl]);      e0hi[j] = (short)f2bf(Wc0[32 + kl]);
        e1lo[j] = (short)f2bf(Wc1[kl]);      e1hi[j] = (short)f2bf(Wc1[32 + kl]);
    }

    const int b = blockIdx.x;
    const int start = offsets[b], end = offsets[b + 1];
    const int nt = (end - start + 63) >> 6;
    const int rowbase = b * BROW;
    const int tgtrow = w16 + l15;       // lane's owned local row (48..63 idle)

    f32x4 aggC[4] = {};                  // wave's 16 rows x 64 feats, C layout

    auto LOADREC = [&](int t) -> uint2 {
        int e = start + t * 64 + w16 + l15;
        if (e < end) return erec[e];
        uint2 s; s.x = 0x0000FFFFu; s.y = 0u; return s;
    };

    if (nt > 0){
        uint2 recA = LOADREC(0);
        uint2 recB = (nt > 1) ? LOADREC(1) : recA;
        bf16x8 u0, u1, v0, v1;
        ISSUE_UV(recA, u0, u1, v0, v1);

        for (int t = 0; t < nt; ++t){
            uint2 recC = LOADREC(t + 2 < nt ? t + 2 : nt - 1);
            bf16x8 nu0, nu1, nv0, nv1;
            ISSUE_UV(recB, nu0, nu1, nv0, nv1);   // next tile's gathers in flight

            int rn_raw = (int)(recA.x & 0xFFFFu);
            float ef0 = bf2f((short)(recA.y & 0xFFFFu));
            float ef1 = bf2f((short)(recA.y >> 16));

            float xl[8], xh[8];
            #pragma unroll
            for (int j = 0; j < 8; ++j){
                float hA = fmaf(ef1, bf2f(e1lo[j]), ef0 * bf2f(e0lo[j]));
                float hB = fmaf(ef1, bf2f(e1hi[j]), ef0 * bf2f(e0hi[j]));
                xl[j] = fmaxf(hA + bf2f(u0[j]) + bf2f(v0[j]), 0.f);
                xh[j] = fmaxf(hB + bf2f(u1[j]) + bf2f(v1[j]), 0.f);
            }
            bf16x8 a0, a1;
            PACK8(a0, xl);
            PACK8(a1, xh);

            f32x4 m[4];
            #pragma unroll
            for (int f = 0; f < 4; ++f){ m[f][0]=bias2[f]; m[f][1]=bias2[f]; m[f][2]=bias2[f]; m[f][3]=bias2[f]; }
            #pragma unroll
            for (int f = 0; f < 4; ++f) m[f] = MFMA16(a0, bW2[0][f], m[f]);
            #pragma unroll
            for (int f = 0; f < 4; ++f) m[f] = MFMA16(a1, bW2[1][f], m[f]);

            // transposed (feat-major) bf16 messages -> LDS
            const int buf = t & 1;
            #pragma unroll
            for (int f = 0; f < 4; ++f){
                uint2 wv;
                wv.x = cvtpk(m[f][0], m[f][1]);
                wv.y = cvtpk(m[f][2], m[f][3]);
                *(uint2*)&sMsgT[buf][(f * 16 + l15) * 72 + w16 + quad * 4] = wv;
            }
            if (quad == 0)
                sRowT[buf][w16 + l15] = (rn_raw == 0xFFFF) ? (u16)0xFFFF
                                                           : (u16)(rn_raw - rowbase);

            __syncthreads();

            // scatter: aggC += S (onehot rows) x M  (2 e-chunks x 4 f-chunks)
            #pragma unroll
            for (int c = 0; c < 2; ++c){
                union { bf16x8 v; unsigned d[4]; } sfr;
                union { uint4 q; unsigned d[4]; } rv;
                rv.q = *(const uint4*)&sRowT[buf][c * 32 + quad * 8];
                #pragma unroll
                for (int k = 0; k < 4; ++k){
                    unsigned d = rv.d[k];
                    unsigned lo = d & 0xFFFFu, hi = d >> 16;
                    sfr.d[k] = (lo == (unsigned)tgtrow ? 0x3F80u : 0u)
                             | (hi == (unsigned)tgtrow ? 0x3F800000u : 0u);
                }
                #pragma unroll
                for (int f = 0; f < 4; ++f){
                    bf16x8 mb = *(const bf16x8*)&sMsgT[buf][(f * 16 + l15) * 72 + c * 32 + quad * 8];
                    aggC[f] = MFMA16(sfr.v, mb, aggC[f]);
                }
            }
            // no 2nd barrier: next tile writes the other buffer

            recA = recB; recB = recC;
            u0 = nu0; u1 = nu1; v0 = nv0; v1 = nv1;
        }
    }

    __syncthreads();                     // all scatter reads done

    if (w < 3){
        // ------------- fused update: h = relu(LN(aggC + h@SW + SB)) ----------
        bf16x8 bW[2][4];
        #pragma unroll
        for (int kk = 0; kk < 2; ++kk)
            #pragma unroll
            for (int f = 0; f < 4; ++f)
                bW[kk][f] = load_bfrag(SW, 64, f * 16 + l15, kk * 32 + quad * 8);
        float sb[4], lg[4], lb[4];
        #pragma unroll
        for (int f = 0; f < 4; ++f){
            int n = f * 16 + l15;
            sb[f] = SB[n]; lg[f] = LG[n]; lb[f] = LB[n];
        }

        const int nbase = rowbase + w16;
        int na = nbase + l15; if (na > N - 1) na = N - 1;
        const u16* pa = hbf + (size_t)na * 64 + quad * 8;
        bf16x8 h0 = *(const bf16x8*)pa;
        bf16x8 h1 = *(const bf16x8*)(pa + 32);

        f32x4 acc[4] = {};
        #pragma unroll
        for (int f = 0; f < 4; ++f) acc[f] = MFMA16(h0, bW[0][f], acc[f]);
        #pragma unroll
        for (int f = 0; f < 4; ++f) acc[f] = MFMA16(h1, bW[1][f], acc[f]);

        float vals[4][4];
        #pragma unroll
        for (int r = 0; r < 4; ++r)
            #pragma unroll
            for (int f = 0; f < 4; ++f)
                vals[f][r] = acc[f][r] + sb[f] + aggC[f][r];

        #pragma unroll
        for (int r = 0; r < 4; ++r){
            float s  = vals[0][r] + vals[1][r] + vals[2][r] + vals[3][r];
            float sq = vals[0][r]*vals[0][r] + vals[1][r]*vals[1][r]
                     + vals[2][r]*vals[2][r] + vals[3][r]*vals[3][r];
            #pragma unroll
            for (int msk = 1; msk < 16; msk <<= 1){
                s  += __shfl_xor(s,  msk);
                sq += __shfl_xor(sq, msk);
            }
            float mean = s * (1.f / 64.f);
            float var  = sq * (1.f / 64.f) - mean * mean;
            float rstd = rsqrtf(var + 1e-5f);
            int node = nbase + quad * 4 + r;
            #pragma unroll
            for (int f = 0; f < 4; ++f){
                float hv = (vals[f][r] - mean) * rstd * lg[f] + lb[f];
                hv = hv > 0.f ? hv : 0.f;
                u16 hb = f2bf(hv);
                sH[(w16 + quad * 4 + r) * 72 + f * 16 + l15] = hb;
                if (node < N) hbf[(size_t)node * 64 + f * 16 + l15] = hb;
            }
        }

        if (cW1){
            bf16x8 bA[2][4], bB[2][4];
            #pragma unroll
            for (int kk = 0; kk < 2; ++kk)
                #pragma unroll
                for (int f = 0; f < 4; ++f){
                    int n = f * 16 + l15, k0 = kk * 32 + quad * 8;
                    bA[kk][f] = load_bfrag(cW1,           64, n, k0);
                    bB[kk][f] = load_bfrag(cW1 + 64 * 64, 64, n, k0);
                }
            float b1n[4];
            #pragma unroll
            for (int f = 0; f < 4; ++f) b1n[f] = cB1[f * 16 + l15];

            bf16x8 a0 = *(const bf16x8*)&sH[(w16 + l15) * 72 + quad * 8];
            bf16x8 a1 = *(const bf16x8*)&sH[(w16 + l15) * 72 + 32 + quad * 8];

            f32x4 ua[4], va[4];
            #pragma unroll
            for (int f = 0; f < 4; ++f){
                ua[f][0]=b1n[f]; ua[f][1]=b1n[f]; ua[f][2]=b1n[f]; ua[f][3]=b1n[f];
                va[f][0]=0.f; va[f][1]=0.f; va[f][2]=0.f; va[f][3]=0.f;
            }
            #pragma unroll
            for (int f = 0; f < 4; ++f){ ua[f] = MFMA16(a0, bA[0][f], ua[f]); va[f] = MFMA16(a0, bB[0][f], va[f]); }
            #pragma unroll
            for (int f = 0; f < 4; ++f){ ua[f] = MFMA16(a1, bA[1][f], ua[f]); va[f] = MFMA16(a1, bB[1][f], va[f]); }

            #pragma unroll
            for (int r = 0; r < 4; ++r){
                int node = nbase + quad * 4 + r;
                if (node < N){
                    #pragma unroll
                    for (int f = 0; f < 4; ++f){
                        Un[(size_t)node * 64 + f * 16 + l15] = f2bf(ua[f][r]);
                        Vn[(size_t)node * 64 + f * 16 + l15] = f2bf(va[f][r]);
                    }
                }
            }
        }
    }
}

// ---------------- head: out = relu(h@W1+b1)@W2 + b2  [N][8] f32 --------------
__global__ __launch_bounds__(256) void head_kernel(
    const u16* __restrict__ hbf,
    const float* __restrict__ W1, const float* __restrict__ B1,
    const float* __restrict__ W2, const float* __restrict__ B2,
    float* __restrict__ out, int N)
{
    __shared__ u16 sT[64 * 72];
    const int tid = threadIdx.x;
    const int w = tid >> 6, l = tid & 63, l15 = l & 15, quad = l >> 4;

    bf16x8 bW1[2][4];
    #pragma unroll
    for (int kk = 0; kk < 2; ++kk)
        #pragma unroll
        for (int f = 0; f < 4; ++f)
            bW1[kk][f] = load_bfrag(W1, 64, f * 16 + l15, kk * 32 + quad * 8);
    float b1v[4];
    #pragma unroll
    for (int f = 0; f < 4; ++f) b1v[f] = B1[f * 16 + l15];

    bf16x8 bW2[2];
    #pragma unroll
    for (int kk = 0; kk < 2; ++kk)
        #pragma unroll
        for (int j = 0; j < 8; ++j){
            int k = kk * 32 + quad * 8 + j;
            bW2[kk][j] = (l15 < 8) ? (short)f2bf(W2[k * 8 + l15]) : (short)0;
        }
    float b2v = (l15 < 8) ? B2[l15] : 0.f;

    const int nbase = blockIdx.x * 64 + w * 16;
    int na = nbase + l15; if (na > N - 1) na = N - 1;
    const u16* pa = hbf + (size_t)na * 64 + quad * 8;
    bf16x8 a0 = *(const bf16x8*)pa;
    bf16x8 a1 = *(const bf16x8*)(pa + 32);

    f32x4 acc[4];
    #pragma unroll
    for (int f = 0; f < 4; ++f){ acc[f][0]=b1v[f]; acc[f][1]=b1v[f]; acc[f][2]=b1v[f]; acc[f][3]=b1v[f]; }
    #pragma unroll
    for (int f = 0; f < 4; ++f) acc[f] = MFMA16(a0, bW1[0][f], acc[f]);
    #pragma unroll
    for (int f = 0; f < 4; ++f) acc[f] = MFMA16(a1, bW1[1][f], acc[f]);

    u16* myT = sT + (w * 16) * 72;
    #pragma unroll
    for (int f = 0; f < 4; ++f)
        #pragma unroll
        for (int r = 0; r < 4; ++r){
            float v = acc[f][r] > 0.f ? acc[f][r] : 0.f;
            myT[(quad * 4 + r) * 72 + f * 16 + l15] = f2bf(v);
        }

    f32x4 o = { b2v, b2v, b2v, b2v };
    #pragma unroll
    for (int kk = 0; kk < 2; ++kk){
        bf16x8 a = *(const bf16x8*)&myT[l15 * 72 + kk * 32 + quad * 8];
        o = MFMA16(a, bW2[kk], o);
    }
    #pragma unroll
    for (int r = 0; r < 4; ++r){
        int node = nbase + quad * 4 + r;
        if (node < N && l15 < 8)
            out[(size_t)node * 8 + l15] = o[r];
    }
}

extern "C" void kernel_launch(void* const* d_in, const int* in_sizes, int n_in,
                              void* d_out, int out_size, void* d_ws, size_t ws_size,
                              hipStream_t stream)
{
    const float* X      = (const float*)d_in[0];
    const int*   EI     = (const int*)d_in[1];
    const float* EF     = (const float*)d_in[2];
    const float* encW1  = (const float*)d_in[4];
    const float* encB1  = (const float*)d_in[5];
    const float* encW2  = (const float*)d_in[6];
    const float* encB2  = (const float*)d_in[7];
    const float* convW1 = (const float*)d_in[8];
    const float* convB1 = (const float*)d_in[9];
    const float* convW2 = (const float*)d_in[10];
    const float* convB2 = (const float*)d_in[11];
    const float* skipW  = (const float*)d_in[12];
    const float* skipB  = (const float*)d_in[13];
    const float* lnG    = (const float*)d_in[14];
    const float* lnB    = (const float*)d_in[15];
    const float* headW1 = (const float*)d_in[16];
    const float* headB1 = (const float*)d_in[17];
    const float* headW2 = (const float*)d_in[18];
    const float* headB2 = (const float*)d_in[19];

    const int N = in_sizes[0] / 3;      // NOTE: packing assumes N < 65535
    const int E = in_sizes[1] / 2;
    const int L = in_sizes[8] / (130 * 64);
    const int* rows = EI;
    const int* cols = EI + E;

    const int NB64 = (N + 63) / 64;     // 64-node tiles (enc/head)
    const int NB48 = (N + 47) / 48;     // 48-row buckets (fused), <= 2048

    auto align256 = [](size_t x){ return (x + 255) & ~(size_t)255; };
    char* p = (char*)d_ws;
    u16* hbf   = (u16*)p;           p += align256((size_t)N * 64 * 2);
    u16* Ubuf0 = (u16*)p;           p += align256((size_t)N * 64 * 2);
    u16* Vbuf0 = (u16*)p;           p += align256((size_t)N * 64 * 2);
    u16* Ubuf1 = (u16*)p;           p += align256((size_t)N * 64 * 2);
    u16* Vbuf1 = (u16*)p;           p += align256((size_t)N * 64 * 2);
    uint2* erec = (uint2*)p;        p += align256((size_t)E * 8);
    int* countsB = (int*)p;         p += align256(2048 * 4);
    int* offsets = (int*)p;         p += align256(2056 * 4);
    int* cursorB = (int*)p;         p += align256(2048 * 4);

    // ---- build 48-row-bucket binned packed edge records (once per call) ----
    hipMemsetAsync(countsB, 0, (size_t)NB48 * sizeof(int), stream);
    countB_kernel<<<256, 256, 0, stream>>>(rows, countsB, E, NB48);
    scanB_kernel<<<1, 1024, 0, stream>>>(countsB, offsets, cursorB, NB48);
    binpack_kernel<<<(E + CHUNK - 1) / CHUNK, 1024, 0, stream>>>(rows, cols, EF, cursorB, erec, E);

    enc_kernel<<<NB64, 256, 0, stream>>>(X, encW1, encB1, encW2, encB2,
                                         convW1, convB1, hbf, Ubuf0, Vbuf0, N);

    u16* Ucur = Ubuf0; u16* Vcur = Vbuf0;
    u16* Ualt = Ubuf1; u16* Valt = Vbuf1;
    for (int li = 0; li < L; ++li){
        const float* w1n = (li + 1 < L) ? convW1 + (size_t)(li + 1) * 130 * 64 : nullptr;
        const float* b1n = (li + 1 < L) ? convB1 + (li + 1) * 64 : nullptr;
        fused_kernel<<<NB48, 256, 0, stream>>>(Ucur, Vcur, erec, offsets,
            convW1 + (size_t)li * 130 * 64,
            convW2 + (size_t)li * 64 * 64, convB2 + li * 64,
            hbf,
            skipW + (size_t)li * 64 * 64, skipB + li * 64,
            lnG + li * 64, lnB + li * 64,
            w1n, b1n, Ualt, Valt, N);
        u16* t;
        t = Ucur; Ucur = Ualt; Ualt = t;
        t = Vcur; Vcur = Valt; Valt = t;
    }
    head_kernel<<<NB64, 256, 0, stream>>>(hbf, headW1, headB1, headW2, headB2,
                                          (float*)d_out, N);
}